// Round 1
// 679.907 us; speedup vs baseline: 1.0868x; 1.0868x over previous
//
#include <hip/hip_runtime.h>
#include <hip/hip_bf16.h>
#include <hip/hip_fp16.h>

// Problem: y[b,s,o] = sum_i x[b,s,i] * w[o,i] + bias[o]
//   w = weight_high + fp32(weight_medium) + (~high & ~medium) * weight_low * low_scale
// M = 4*2048 = 8192, N = 4096, K = 4096.
// This round: replace the 128x128 vmcnt(0)-per-K-step GEMM (774 TF, MfmaUtil 34%,
// 3.35e7 bank conflicts) with a 256x256 counted-vmcnt pipeline:
//   BK=32, 4 LDS K-tile buffers (128 KiB), depth-3 prefetch, 1 barrier/K-tile,
//   st_16x32 XOR swizzle (T2), setprio around MFMA (T5), XCD block swizzle (T1).

#define M_DIM 8192
#define N_DIM 4096
#define K_DIM 4096

typedef __attribute__((ext_vector_type(8))) short short8;
typedef __attribute__((ext_vector_type(4))) float floatx4;
typedef __attribute__((ext_vector_type(8))) _Float16 half8;
typedef __attribute__((ext_vector_type(8))) unsigned char uchar8;
typedef __attribute__((ext_vector_type(4))) int intx4;

__device__ inline unsigned short f2bf(float f) {
    union { float f; unsigned u; } v; v.f = f;
    return (unsigned short)((v.u + 0x7fffu + ((v.u >> 16) & 1u)) >> 16);  // RNE
}

__device__ inline void async16(const void* g, const void* l) {
    __builtin_amdgcn_global_load_lds(
        (const __attribute__((address_space(1))) void*)g,
        (__attribute__((address_space(3))) void*)l,
        16, 0, 0);
}

// ---------- dtype-normalization probe ----------
__global__ __launch_bounds__(256) void detect_kernel(const unsigned* __restrict__ wm_raw,
                                                     const unsigned* __restrict__ hm_raw,
                                                     int* __restrict__ flags) {
    __shared__ int s_f32cnt, s_maskbig;
    if (threadIdx.x == 0) { s_f32cnt = 0; s_maskbig = 0; }
    __syncthreads();
    union { unsigned u; float f; } w; w.u = wm_raw[threadIdx.x];
    float av = fabsf(w.f);
    if (av > 1e-4f && av < 1.0f) atomicAdd(&s_f32cnt, 1);
    if (hm_raw[threadIdx.x] > 1u) atomicAdd(&s_maskbig, 1);
    __syncthreads();
    if (threadIdx.x == 0) {
        flags[0] = (s_f32cnt >= 8) ? 1 : 0;
        flags[1] = (s_maskbig > 0) ? 1 : 0;
    }
}

// ---------- x fp32 -> bf16 ----------
__global__ __launch_bounds__(256) void cvt_x_kernel(const float* __restrict__ x,
                                                    unsigned short* __restrict__ o) {
    const int i = (blockIdx.x * 256 + threadIdx.x) * 8;
    floatx4 f0 = *(const floatx4*)(x + i);
    floatx4 f1 = *(const floatx4*)(x + i + 4);
    short8 s;
    s[0] = (short)f2bf(f0[0]); s[1] = (short)f2bf(f0[1]);
    s[2] = (short)f2bf(f0[2]); s[3] = (short)f2bf(f0[3]);
    s[4] = (short)f2bf(f1[0]); s[5] = (short)f2bf(f1[1]);
    s[6] = (short)f2bf(f1[2]); s[7] = (short)f2bf(f1[3]);
    *(short8*)(o + i) = s;
}

// ---------- w reconstruct -> bf16 ----------
__global__ __launch_bounds__(256) void build_w_kernel(
        const float* __restrict__ wh, const void* __restrict__ wm_raw,
        const int* __restrict__ wl, const void* __restrict__ hm_raw,
        const void* __restrict__ mm_raw, const float* __restrict__ scale_p,
        const int* __restrict__ flags, unsigned short* __restrict__ o) {
    const int i = (blockIdx.x * 256 + threadIdx.x) * 8;
    const float scale = *scale_p;
    const bool wm_f32  = flags[0] != 0;
    const bool mask_u8 = flags[1] != 0;

    floatx4 h0 = *(const floatx4*)(wh + i);
    floatx4 h1 = *(const floatx4*)(wh + i + 4);
    intx4  l0 = *(const intx4*)(wl + i);
    intx4  l1 = *(const intx4*)(wl + i + 4);

    float mv[8];
    if (wm_f32) {
        floatx4 m0 = *(const floatx4*)((const float*)wm_raw + i);
        floatx4 m1 = *(const floatx4*)((const float*)wm_raw + i + 4);
#pragma unroll
        for (int e = 0; e < 4; ++e) { mv[e] = m0[e]; mv[e + 4] = m1[e]; }
    } else {
        half8 m = *(const half8*)((const _Float16*)wm_raw + i);
#pragma unroll
        for (int e = 0; e < 8; ++e) mv[e] = (float)m[e];
    }

    int lowmask[8];
    if (mask_u8) {
        uchar8 a = *(const uchar8*)((const unsigned char*)hm_raw + i);
        uchar8 b = *(const uchar8*)((const unsigned char*)mm_raw + i);
#pragma unroll
        for (int e = 0; e < 8; ++e) lowmask[e] = (a[e] | b[e]) == 0;
    } else {
        intx4 a0 = *(const intx4*)((const int*)hm_raw + i);
        intx4 a1 = *(const intx4*)((const int*)hm_raw + i + 4);
        intx4 b0 = *(const intx4*)((const int*)mm_raw + i);
        intx4 b1 = *(const intx4*)((const int*)mm_raw + i + 4);
#pragma unroll
        for (int e = 0; e < 4; ++e) {
            lowmask[e]     = (a0[e] | b0[e]) == 0;
            lowmask[e + 4] = (a1[e] | b1[e]) == 0;
        }
    }

    short8 s;
#pragma unroll
    for (int e = 0; e < 8; ++e) {
        float v = (e < 4 ? h0[e] : h1[e - 4]) + mv[e];
        int   lw = (e < 4 ? l0[e] : l1[e - 4]);
        if (lowmask[e]) v += (float)lw * scale;
        s[e] = (short)f2bf(v);
    }
    *(short8*)(o + i) = s;
}

// ---------- 256x256 GEMM, BK=32, 4-buffer counted-vmcnt pipeline ----------
// C[m,n] = sum_k A[m,k]*B[n,k] + bias[n] (A,B bf16 row-major [*,K], C fp32)
// 512 threads = 8 waves in a 2(M)x4(N) grid; per-wave output 128x64.
// LDS: 4 buffers x (A 16KB + B 16KB) = 128 KiB dynamic.
// Per K-tile(32): stage 4x async16/thread, vmcnt(8) keeps 2 tiles in flight.
// Swizzle: physical_byte = logical_byte ^ (((logical_byte>>9)&1)<<5) within each
// 16-row x 64B region; applied on ds_read addr AND (inverse == same) on the
// per-lane global source of global_load_lds (LDS dest stays linear).
__global__ __launch_bounds__(512, 2) void gemm256_kernel(
        const unsigned short* __restrict__ A,   // [M,K] bf16
        const unsigned short* __restrict__ Bw,  // [N,K] bf16
        const float* __restrict__ bias,
        float* __restrict__ out) {
    extern __shared__ char smem[];
    const int tid  = threadIdx.x;
    const int wave = tid >> 6, lane = tid & 63;
    const int lrow = lane & 15, lquad = lane >> 4;

    // XCD-bijective swizzle: 512 blocks, 64 per XCD; within an XCD tn varies
    // fastest so consecutive co-resident blocks share the 2MB A panel in L2.
    const int wg  = blockIdx.x;
    const int swz = (wg & 7) * 64 + (wg >> 3);
    const int bm0 = (swz >> 4) * 256;   // M/256 = 32 row-tiles
    const int bn0 = (swz & 15) * 256;   // N/256 = 16 col-tiles

    const int wr = wave >> 2, wc = wave & 3;
    const int wm = wr * 128, wn = wc * 64;

    // ---- staging: linear LDS dest, pre-swizzled per-lane global source ----
    // lds byte p = s*8192 + wave*1024 + lane*16 ; logical q = p ^ ((p>>9&1)<<5)
    //  => lane' = lane ^ (lane>=32 ? 2 : 0)
    const int lane2 = lane ^ ((lane & 32) ? 2 : 0);
    const int srow  = wave * 16 + (lane2 >> 2);   // 0..127
    const int scol  = (lane2 & 3) * 8;            // 0,8,16,24
    const unsigned short* gA0 = A  + (size_t)(bm0 + srow) * K_DIM + scol;
    const unsigned short* gA1 = gA0 + (size_t)128 * K_DIM;
    const unsigned short* gB0 = Bw + (size_t)(bn0 + srow) * K_DIM + scol;
    const unsigned short* gB1 = gB0 + (size_t)128 * K_DIM;
    const int dstA = wave * 1024;   // wave-uniform LDS byte offset
    unsigned ko = 0;                // k element offset, +32 per staged tile

    // ---- swizzled LDS read byte offsets (per buffer; A at +0, B at +16384) ----
    int offA[8], offB[4];
#pragma unroll
    for (int i = 0; i < 8; ++i) {
        int q = (wm + i * 16 + lrow) * 64 + lquad * 16;
        offA[i] = q ^ (((q >> 9) & 1) << 5);
    }
#pragma unroll
    for (int j = 0; j < 4; ++j) {
        int q = (wn + j * 16 + lrow) * 64 + lquad * 16;
        offB[j] = 16384 + (q ^ (((q >> 9) & 1) << 5));
    }

    floatx4 acc[8][4] = {};

#define STAGE(buf) do { \
        char* d_ = smem + (buf) * 32768 + dstA; \
        async16(gA0 + ko, d_); \
        async16(gA1 + ko, d_ + 8192); \
        async16(gB0 + ko, d_ + 16384); \
        async16(gB1 + ko, d_ + 24576); \
        ko += 32; } while (0)

#define COMPUTE(buf) do { \
        const char* ab_ = smem + (buf) * 32768; \
        short8 af[8], bq[4]; \
        _Pragma("unroll") \
        for (int i = 0; i < 8; ++i) af[i] = *(const short8*)(ab_ + offA[i]); \
        _Pragma("unroll") \
        for (int j = 0; j < 4; ++j) bq[j] = *(const short8*)(ab_ + offB[j]); \
        __builtin_amdgcn_s_setprio(1); \
        _Pragma("unroll") \
        for (int i = 0; i < 8; ++i) \
            _Pragma("unroll") \
            for (int j = 0; j < 4; ++j) \
                acc[i][j] = __builtin_amdgcn_mfma_f32_16x16x32_bf16(af[i], bq[j], acc[i][j], 0, 0, 0); \
        __builtin_amdgcn_s_setprio(0); } while (0)

#define WAITV(n) asm volatile("s_waitcnt vmcnt(" #n ")" ::: "memory")
#define BAR() do { __builtin_amdgcn_s_barrier(); asm volatile("" ::: "memory"); } while (0)

    // prologue: tiles 0,1,2 in flight (12 loads/thread)
    STAGE(0); STAGE(1); STAGE(2);

    const int NT = K_DIM / 32;  // 128
    // steady state: entering iter t, tiles t..t+2 outstanding (12 loads).
    // vmcnt(8) drains tile t; barrier publishes it to all waves AND separates
    // all waves' reads(t-1) from the stage issued into buf[(t-1)&3] below.
    for (int t = 0; t < NT - 3; ++t) {
        WAITV(8);
        BAR();
        STAGE((t + 3) & 3);
        COMPUTE(t & 3);
    }
    WAITV(8); BAR(); COMPUTE((NT - 3) & 3);   // 12 outstanding -> drain NT-3
    WAITV(4); BAR(); COMPUTE((NT - 2) & 3);   //  8 outstanding -> drain NT-2
    WAITV(0); BAR(); COMPUTE((NT - 1) & 3);   //  4 outstanding -> drain NT-1

#undef STAGE
#undef COMPUTE
#undef WAITV
#undef BAR

    // epilogue (verified 16x16 C/D layout: col = lane&15, row = lquad*4 + r)
#pragma unroll
    for (int j = 0; j < 4; ++j) {
        const int col = bn0 + wn + j * 16 + lrow;
        const float bv = bias[col];
#pragma unroll
        for (int i = 0; i < 8; ++i) {
            const int row = bm0 + wm + i * 16 + lquad * 4;
#pragma unroll
            for (int r = 0; r < 4; ++r)
                out[(size_t)(row + r) * N_DIM + col] = acc[i][j][r] + bv;
        }
    }
}

// ---------- fallback: A staged from fp32 inline (small-ws path) ----------
__global__ __launch_bounds__(256) void gemm_fused_kernel(
        const float* __restrict__ X,            // [M,K] fp32
        const unsigned short* __restrict__ Bw,  // [N,K] bf16
        const float* __restrict__ bias,
        float* __restrict__ out) {
    __shared__ unsigned short As[128 * 32];
    __shared__ unsigned short Bs[128 * 32];
    const int tid  = threadIdx.x;
    const int wave = tid >> 6, lane = tid & 63;
    const int bm0 = blockIdx.y * 128, bn0 = blockIdx.x * 128;
    const int wm = (wave >> 1) * 64, wn = (wave & 1) * 64;
    const int lrow = lane & 15, lquad = lane >> 4;
    const int arow = tid >> 1, acol = (tid & 1) * 16;

    floatx4 acc[4][4] = {};

    for (int k0 = 0; k0 < K_DIM; k0 += 32) {
        __syncthreads();
#pragma unroll
        for (int c = 0; c < 2; ++c) {
            const int lb  = wave * 2048 + c * 1024;
            const int e   = (lb >> 1) + lane * 8;
            const int row = e >> 5, col = e & 31;
            async16(Bw + (size_t)(bn0 + row) * K_DIM + k0 + col, (const char*)Bs + lb);
        }
        {
            const float* g = X + (size_t)(bm0 + arow) * K_DIM + k0 + acol;
            floatx4 f0 = *(const floatx4*)(g);
            floatx4 f1 = *(const floatx4*)(g + 4);
            floatx4 f2 = *(const floatx4*)(g + 8);
            floatx4 f3 = *(const floatx4*)(g + 12);
            short8 s0, s1;
            s0[0]=(short)f2bf(f0[0]); s0[1]=(short)f2bf(f0[1]); s0[2]=(short)f2bf(f0[2]); s0[3]=(short)f2bf(f0[3]);
            s0[4]=(short)f2bf(f1[0]); s0[5]=(short)f2bf(f1[1]); s0[6]=(short)f2bf(f1[2]); s0[7]=(short)f2bf(f1[3]);
            s1[0]=(short)f2bf(f2[0]); s1[1]=(short)f2bf(f2[1]); s1[2]=(short)f2bf(f2[2]); s1[3]=(short)f2bf(f2[3]);
            s1[4]=(short)f2bf(f3[0]); s1[5]=(short)f2bf(f3[1]); s1[6]=(short)f2bf(f3[2]); s1[7]=(short)f2bf(f3[3]);
            *(short8*)&As[arow * 32 + acol]     = s0;
            *(short8*)&As[arow * 32 + acol + 8] = s1;
        }
        __syncthreads();

        short8 af[4], bf[4];
#pragma unroll
        for (int i = 0; i < 4; ++i)
            af[i] = *(const short8*)&As[(wm + i * 16 + lrow) * 32 + lquad * 8];
#pragma unroll
        for (int j = 0; j < 4; ++j)
            bf[j] = *(const short8*)&Bs[(wn + j * 16 + lrow) * 32 + lquad * 8];
#pragma unroll
        for (int i = 0; i < 4; ++i)
#pragma unroll
            for (int j = 0; j < 4; ++j)
                acc[i][j] = __builtin_amdgcn_mfma_f32_16x16x32_bf16(af[i], bf[j], acc[i][j], 0, 0, 0);
    }

#pragma unroll
    for (int j = 0; j < 4; ++j) {
        const int col = bn0 + wn + j * 16 + lrow;
        const float bv = bias[col];
#pragma unroll
        for (int i = 0; i < 4; ++i) {
            const int row = bm0 + wm + i * 16 + lquad * 4;
#pragma unroll
            for (int r = 0; r < 4; ++r)
                out[(size_t)(row + r) * N_DIM + col] = acc[i][j][r] + bv;
        }
    }
}

extern "C" void kernel_launch(void* const* d_in, const int* in_sizes, int n_in,
                              void* d_out, int out_size, void* d_ws, size_t ws_size,
                              hipStream_t stream) {
    const float*    x     = (const float*)d_in[0];
    const float*    wh    = (const float*)d_in[1];
    const void*     wmed  = d_in[2];           // fp32 or fp16 — detected on device
    const int*      wl    = (const int*)d_in[3];
    const void*     hm    = d_in[4];           // int32 or uint8 — detected on device
    const void*     mm    = d_in[5];
    const float*    scale = (const float*)d_in[6];
    const float*    bias  = (const float*)d_in[7];
    float*          out   = (float*)d_out;

    int*            flags = (int*)d_ws;                                   // 256 B reserved
    unsigned short* wbf   = (unsigned short*)((char*)d_ws + 256);         // 32 MB
    unsigned short* xbf   = (unsigned short*)((char*)d_ws + 256 + (size_t)N_DIM * K_DIM * 2);
    const size_t need_full = 256 + (size_t)N_DIM * K_DIM * 2 + (size_t)M_DIM * K_DIM * 2;

    static bool attr_done = false;
    if (!attr_done) {
        (void)hipFuncSetAttribute(reinterpret_cast<const void*>(gemm256_kernel),
                                  hipFuncAttributeMaxDynamicSharedMemorySize, 131072);
        attr_done = true;
    }

    detect_kernel<<<1, 256, 0, stream>>>((const unsigned*)wmed, (const unsigned*)hm, flags);
    build_w_kernel<<<N_DIM * K_DIM / 2048, 256, 0, stream>>>(wh, wmed, wl, hm, mm, scale, flags, wbf);

    if (ws_size >= need_full) {
        cvt_x_kernel<<<M_DIM * K_DIM / 2048, 256, 0, stream>>>(x, xbf);
        gemm256_kernel<<<dim3(512), dim3(512), 131072, stream>>>(xbf, wbf, bias, out);
    } else {
        dim3 grid(N_DIM / 128, M_DIM / 128);
        gemm_fused_kernel<<<grid, 256, 0, stream>>>(x, wbf, bias, out);
    }
}

// Round 2
// 675.059 us; speedup vs baseline: 1.0946x; 1.0072x over previous
//
#include <hip/hip_runtime.h>
#include <hip/hip_bf16.h>
#include <hip/hip_fp16.h>

// Problem: y[b,s,o] = sum_i x[b,s,i] * w[o,i] + bias[o]
//   w = weight_high + fp32(weight_medium) + (~high & ~medium) * weight_low * low_scale
// M = 4*2048 = 8192, N = 4096, K = 4096.
// Round 2: (a) split each K-tile of the 256x256 counted-vmcnt GEMM into two
// {ds_read pre-barrier -> bar -> lgkmcnt(0) -> 16 MFMA} phases (m201-style) so
// LDS reads overlap other waves' MFMA; (b) fuse detect+build_w+cvt_x into one
// prep kernel (per-block ballot dtype detection, block-range split).

#define M_DIM 8192
#define N_DIM 4096
#define K_DIM 4096

typedef __attribute__((ext_vector_type(8))) short short8;
typedef __attribute__((ext_vector_type(4))) float floatx4;
typedef __attribute__((ext_vector_type(8))) _Float16 half8;
typedef __attribute__((ext_vector_type(8))) unsigned char uchar8;
typedef __attribute__((ext_vector_type(4))) int intx4;

__device__ inline unsigned short f2bf(float f) {
    union { float f; unsigned u; } v; v.f = f;
    return (unsigned short)((v.u + 0x7fffu + ((v.u >> 16) & 1u)) >> 16);  // RNE
}

__device__ inline void async16(const void* g, const void* l) {
    __builtin_amdgcn_global_load_lds(
        (const __attribute__((address_space(1))) void*)g,
        (__attribute__((address_space(3))) void*)l,
        16, 0, 0);
}

// ---------- fused prep: dtype-detect (per-block ballot) + w reconstruct + x cvt ----------
// blocks [0, 8192)        : wbf[i] = bf16(wh + wm + lowmask*wl*scale), 8 elems/thread
// blocks [8192, 24576)    : xbf[i] = bf16(x[i]), 8 elems/thread
__global__ __launch_bounds__(256) void prep_kernel(
        const float* __restrict__ x,
        const float* __restrict__ wh, const void* __restrict__ wm_raw,
        const int* __restrict__ wl, const void* __restrict__ hm_raw,
        const void* __restrict__ mm_raw, const float* __restrict__ scale_p,
        unsigned short* __restrict__ wbf, unsigned short* __restrict__ xbf) {
    const int bid = blockIdx.x;
    const int tid = threadIdx.x;

    if (bid >= 8192) {
        // ---- x fp32 -> bf16 ----
        const size_t i = ((size_t)(bid - 8192) * 256 + tid) * 8;
        floatx4 f0 = *(const floatx4*)(x + i);
        floatx4 f1 = *(const floatx4*)(x + i + 4);
        short8 s;
        s[0] = (short)f2bf(f0[0]); s[1] = (short)f2bf(f0[1]);
        s[2] = (short)f2bf(f0[2]); s[3] = (short)f2bf(f0[3]);
        s[4] = (short)f2bf(f1[0]); s[5] = (short)f2bf(f1[1]);
        s[6] = (short)f2bf(f1[2]); s[7] = (short)f2bf(f1[3]);
        *(short8*)(xbf + i) = s;
        return;
    }

    // ---- dtype flags, derived per-block from the first 64 words (L2 broadcast) ----
    // wm fp32?  fp32 weights ~0.02 land in (1e-4,1); fp16-pairs-as-fp32 never do.
    // mask u8?  int32 bools are only 0/1 per word; packed u8 bools exceed 1.
    const int lane = tid & 63;
    union { unsigned u; float f; } pw; pw.u = ((const unsigned*)wm_raw)[lane];
    const float pav = fabsf(pw.f);
    const bool wm_f32  = __popcll(__ballot(pav > 1e-4f && pav < 1.0f)) >= 4;
    const bool mask_u8 = __ballot(((const unsigned*)hm_raw)[lane] > 1u) != 0;

    const size_t i = ((size_t)bid * 256 + tid) * 8;
    const float scale = *scale_p;

    floatx4 h0 = *(const floatx4*)(wh + i);
    floatx4 h1 = *(const floatx4*)(wh + i + 4);
    intx4  l0 = *(const intx4*)(wl + i);
    intx4  l1 = *(const intx4*)(wl + i + 4);

    float mv[8];
    if (wm_f32) {
        floatx4 m0 = *(const floatx4*)((const float*)wm_raw + i);
        floatx4 m1 = *(const floatx4*)((const float*)wm_raw + i + 4);
#pragma unroll
        for (int e = 0; e < 4; ++e) { mv[e] = m0[e]; mv[e + 4] = m1[e]; }
    } else {
        half8 m = *(const half8*)((const _Float16*)wm_raw + i);
#pragma unroll
        for (int e = 0; e < 8; ++e) mv[e] = (float)m[e];
    }

    int lowmask[8];
    if (mask_u8) {
        uchar8 a = *(const uchar8*)((const unsigned char*)hm_raw + i);
        uchar8 b = *(const uchar8*)((const unsigned char*)mm_raw + i);
#pragma unroll
        for (int e = 0; e < 8; ++e) lowmask[e] = (a[e] | b[e]) == 0;
    } else {
        intx4 a0 = *(const intx4*)((const int*)hm_raw + i);
        intx4 a1 = *(const intx4*)((const int*)hm_raw + i + 4);
        intx4 b0 = *(const intx4*)((const int*)mm_raw + i);
        intx4 b1 = *(const intx4*)((const int*)mm_raw + i + 4);
#pragma unroll
        for (int e = 0; e < 4; ++e) {
            lowmask[e]     = (a0[e] | b0[e]) == 0;
            lowmask[e + 4] = (a1[e] | b1[e]) == 0;
        }
    }

    short8 s;
#pragma unroll
    for (int e = 0; e < 8; ++e) {
        float v = (e < 4 ? h0[e] : h1[e - 4]) + mv[e];
        int   lw = (e < 4 ? l0[e] : l1[e - 4]);
        if (lowmask[e]) v += (float)lw * scale;
        s[e] = (short)f2bf(v);
    }
    *(short8*)(wbf + i) = s;
}

// ---------- 256x256 GEMM, BK=32, 4-buffer counted-vmcnt, 2-phase per K-tile ----------
// C[m,n] = sum_k A[m,k]*B[n,k] + bias[n] (A,B bf16 row-major [*,K], C fp32)
// 512 threads = 8 waves (2M x 4N); per-wave output 128x64.
// LDS: 4 buffers x (A 16KB + B 16KB) = 128 KiB dynamic, 1 block/CU.
// Pipeline ledger (unchanged from round 1, proven): 4 loads/thread/tile, tiles
// t..t+2 in flight at iter top (12 outstanding); WAITV(8) drains tile t only.
// Stage(t+3) -> buf[(t-1)&3], issued after the top barrier which postdates all
// reads of tile t-1. New: each tile computes as two phases, reads issued
// PRE-barrier so their LDS execution overlaps other waves' MFMA.
__global__ __launch_bounds__(512, 2) void gemm256_kernel(
        const unsigned short* __restrict__ A,   // [M,K] bf16
        const unsigned short* __restrict__ Bw,  // [N,K] bf16
        const float* __restrict__ bias,
        float* __restrict__ out) {
    extern __shared__ char smem[];
    const int tid  = threadIdx.x;
    const int wave = tid >> 6, lane = tid & 63;
    const int lrow = lane & 15, lquad = lane >> 4;

    // XCD-bijective swizzle: 512 blocks, 64 per XCD; bn varies fastest within
    // an XCD so co-resident blocks share the A panel in L2.
    const int wg  = blockIdx.x;
    const int swz = (wg & 7) * 64 + (wg >> 3);
    const int bm0 = (swz >> 4) * 256;   // 32 row-tiles
    const int bn0 = (swz & 15) * 256;   // 16 col-tiles

    const int wr = wave >> 2, wc = wave & 3;
    const int wm = wr * 128, wn = wc * 64;

    // staging: linear LDS dest, pre-swizzled per-lane global source
    const int lane2 = lane ^ ((lane & 32) ? 2 : 0);
    const int srow  = wave * 16 + (lane2 >> 2);   // 0..127
    const int scol  = (lane2 & 3) * 8;            // 0,8,16,24
    const unsigned short* gA0 = A  + (size_t)(bm0 + srow) * K_DIM + scol;
    const unsigned short* gA1 = gA0 + (size_t)128 * K_DIM;
    const unsigned short* gB0 = Bw + (size_t)(bn0 + srow) * K_DIM + scol;
    const unsigned short* gB1 = gB0 + (size_t)128 * K_DIM;
    const int dstA = wave * 1024;   // wave-uniform LDS byte offset

    // swizzled LDS read byte offsets (A at +0, B at +16384 within a buffer)
    int offA[8], offB[4];
#pragma unroll
    for (int i = 0; i < 8; ++i) {
        int q = (wm + i * 16 + lrow) * 64 + lquad * 16;
        offA[i] = q ^ (((q >> 9) & 1) << 5);
    }
#pragma unroll
    for (int j = 0; j < 4; ++j) {
        int q = (wn + j * 16 + lrow) * 64 + lquad * 16;
        offB[j] = 16384 + (q ^ (((q >> 9) & 1) << 5));
    }

    floatx4 acc[8][4] = {};

#define STAGEF(TILE) do { \
        char* d_ = smem + ((TILE) & 3) * 32768 + dstA; \
        const unsigned ko_ = (unsigned)(TILE) * 32u; \
        async16(gA0 + ko_, d_); async16(gA1 + ko_, d_ + 8192); \
        async16(gB0 + ko_, d_ + 16384); async16(gB1 + ko_, d_ + 24576); } while (0)

#define WAITV(n) asm volatile("s_waitcnt vmcnt(" #n ")" ::: "memory")
#define BAR() do { __builtin_amdgcn_s_barrier(); asm volatile("" ::: "memory"); } while (0)
#define LGKM0() asm volatile("s_waitcnt lgkmcnt(0)" ::: "memory")
#define SCHED0() __builtin_amdgcn_sched_barrier(0)

// Two phases per K-tile. Phase 1: read A0-3 + B0-3 (8 b128) and issue the
// A-half of stage(T+3) pre-barrier; MFMA the top 64x64 half. Phase 2: read
// A4-7 (4 b128, B reused in regs) + B-half stage; MFMA the bottom half.
#define PHASES(T, DO_STAGE) do { \
        const char* ab_ = smem + ((T) & 3) * 32768; \
        const unsigned ko3_ = ((unsigned)(T) + 3u) * 32u; \
        short8 af_[4], bq_[4], ag_[4]; \
        _Pragma("unroll") \
        for (int i_ = 0; i_ < 4; ++i_) af_[i_] = *(const short8*)(ab_ + offA[i_]); \
        _Pragma("unroll") \
        for (int j_ = 0; j_ < 4; ++j_) bq_[j_] = *(const short8*)(ab_ + offB[j_]); \
        if (DO_STAGE) { char* d_ = smem + (((T) + 3) & 3) * 32768 + dstA; \
            async16(gA0 + ko3_, d_); async16(gA1 + ko3_, d_ + 8192); } \
        SCHED0(); \
        BAR(); \
        LGKM0(); \
        SCHED0(); \
        __builtin_amdgcn_s_setprio(1); \
        _Pragma("unroll") \
        for (int i_ = 0; i_ < 4; ++i_) \
            _Pragma("unroll") \
            for (int j_ = 0; j_ < 4; ++j_) \
                acc[i_][j_] = __builtin_amdgcn_mfma_f32_16x16x32_bf16(af_[i_], bq_[j_], acc[i_][j_], 0, 0, 0); \
        __builtin_amdgcn_s_setprio(0); \
        _Pragma("unroll") \
        for (int i_ = 0; i_ < 4; ++i_) ag_[i_] = *(const short8*)(ab_ + offA[4 + i_]); \
        if (DO_STAGE) { char* d_ = smem + (((T) + 3) & 3) * 32768 + dstA; \
            async16(gB0 + ko3_, d_ + 16384); async16(gB1 + ko3_, d_ + 24576); } \
        SCHED0(); \
        BAR(); \
        LGKM0(); \
        SCHED0(); \
        __builtin_amdgcn_s_setprio(1); \
        _Pragma("unroll") \
        for (int i_ = 0; i_ < 4; ++i_) \
            _Pragma("unroll") \
            for (int j_ = 0; j_ < 4; ++j_) \
                acc[4 + i_][j_] = __builtin_amdgcn_mfma_f32_16x16x32_bf16(ag_[i_], bq_[j_], acc[4 + i_][j_], 0, 0, 0); \
        __builtin_amdgcn_s_setprio(0); \
    } while (0)

    // prologue: tiles 0,1,2 in flight (12 loads/thread)
    STAGEF(0); STAGEF(1); STAGEF(2);

    const int NT = K_DIM / 32;  // 128
    for (int t = 0; t < NT - 3; ++t) {
        WAITV(8);               // drain tile t; t+1,t+2 stay in flight
        BAR();                  // tile t visible to all waves
        PHASES(t, true);
    }
    WAITV(8); BAR(); PHASES(NT - 3, false);
    WAITV(4); BAR(); PHASES(NT - 2, false);
    WAITV(0); BAR(); PHASES(NT - 1, false);

#undef STAGEF
#undef PHASES
#undef WAITV
#undef BAR
#undef LGKM0
#undef SCHED0

    // epilogue (verified 16x16 C/D layout: col = lane&15, row = lquad*4 + r)
#pragma unroll
    for (int j = 0; j < 4; ++j) {
        const int col = bn0 + wn + j * 16 + lrow;
        const float bv = bias[col];
#pragma unroll
        for (int i = 0; i < 8; ++i) {
            const int row = bm0 + wm + i * 16 + lquad * 4;
#pragma unroll
            for (int r = 0; r < 4; ++r)
                out[(size_t)(row + r) * N_DIM + col] = acc[i][j][r] + bv;
        }
    }
}

// ---------- fallback: A staged from fp32 inline (small-ws path) ----------
__global__ __launch_bounds__(256) void gemm_fused_kernel(
        const float* __restrict__ X,            // [M,K] fp32
        const unsigned short* __restrict__ Bw,  // [N,K] bf16
        const float* __restrict__ bias,
        float* __restrict__ out) {
    __shared__ unsigned short As[128 * 32];
    __shared__ unsigned short Bs[128 * 32];
    const int tid  = threadIdx.x;
    const int wave = tid >> 6, lane = tid & 63;
    const int bm0 = blockIdx.y * 128, bn0 = blockIdx.x * 128;
    const int wm = (wave >> 1) * 64, wn = (wave & 1) * 64;
    const int lrow = lane & 15, lquad = lane >> 4;
    const int arow = tid >> 1, acol = (tid & 1) * 16;

    floatx4 acc[4][4] = {};

    for (int k0 = 0; k0 < K_DIM; k0 += 32) {
        __syncthreads();
#pragma unroll
        for (int c = 0; c < 2; ++c) {
            const int lb  = wave * 2048 + c * 1024;
            const int e   = (lb >> 1) + lane * 8;
            const int row = e >> 5, col = e & 31;
            async16(Bw + (size_t)(bn0 + row) * K_DIM + k0 + col, (const char*)Bs + lb);
        }
        {
            const float* g = X + (size_t)(bm0 + arow) * K_DIM + k0 + acol;
            floatx4 f0 = *(const floatx4*)(g);
            floatx4 f1 = *(const floatx4*)(g + 4);
            floatx4 f2 = *(const floatx4*)(g + 8);
            floatx4 f3 = *(const floatx4*)(g + 12);
            short8 s0, s1;
            s0[0]=(short)f2bf(f0[0]); s0[1]=(short)f2bf(f0[1]); s0[2]=(short)f2bf(f0[2]); s0[3]=(short)f2bf(f0[3]);
            s0[4]=(short)f2bf(f1[0]); s0[5]=(short)f2bf(f1[1]); s0[6]=(short)f2bf(f1[2]); s0[7]=(short)f2bf(f1[3]);
            s1[0]=(short)f2bf(f2[0]); s1[1]=(short)f2bf(f2[1]); s1[2]=(short)f2bf(f2[2]); s1[3]=(short)f2bf(f2[3]);
            s1[4]=(short)f2bf(f3[0]); s1[5]=(short)f2bf(f3[1]); s1[6]=(short)f2bf(f3[2]); s1[7]=(short)f2bf(f3[3]);
            *(short8*)&As[arow * 32 + acol]     = s0;
            *(short8*)&As[arow * 32 + acol + 8] = s1;
        }
        __syncthreads();

        short8 af[4], bf[4];
#pragma unroll
        for (int i = 0; i < 4; ++i)
            af[i] = *(const short8*)&As[(wm + i * 16 + lrow) * 32 + lquad * 8];
#pragma unroll
        for (int j = 0; j < 4; ++j)
            bf[j] = *(const short8*)&Bs[(wn + j * 16 + lrow) * 32 + lquad * 8];
#pragma unroll
        for (int i = 0; i < 4; ++i)
#pragma unroll
            for (int j = 0; j < 4; ++j)
                acc[i][j] = __builtin_amdgcn_mfma_f32_16x16x32_bf16(af[i], bf[j], acc[i][j], 0, 0, 0);
    }

#pragma unroll
    for (int j = 0; j < 4; ++j) {
        const int col = bn0 + wn + j * 16 + lrow;
        const float bv = bias[col];
#pragma unroll
        for (int i = 0; i < 4; ++i) {
            const int row = bm0 + wm + i * 16 + lquad * 4;
#pragma unroll
            for (int r = 0; r < 4; ++r)
                out[(size_t)(row + r) * N_DIM + col] = acc[i][j][r] + bv;
        }
    }
}

extern "C" void kernel_launch(void* const* d_in, const int* in_sizes, int n_in,
                              void* d_out, int out_size, void* d_ws, size_t ws_size,
                              hipStream_t stream) {
    const float*    x     = (const float*)d_in[0];
    const float*    wh    = (const float*)d_in[1];
    const void*     wmed  = d_in[2];           // fp32 or fp16 — detected on device
    const int*      wl    = (const int*)d_in[3];
    const void*     hm    = d_in[4];           // int32 or uint8 — detected on device
    const void*     mm    = d_in[5];
    const float*    scale = (const float*)d_in[6];
    const float*    bias  = (const float*)d_in[7];
    float*          out   = (float*)d_out;

    unsigned short* wbf   = (unsigned short*)((char*)d_ws + 256);         // 32 MB
    unsigned short* xbf   = (unsigned short*)((char*)d_ws + 256 + (size_t)N_DIM * K_DIM * 2);
    const size_t need_full = 256 + (size_t)N_DIM * K_DIM * 2 + (size_t)M_DIM * K_DIM * 2;

    static bool attr_done = false;
    if (!attr_done) {
        (void)hipFuncSetAttribute(reinterpret_cast<const void*>(gemm256_kernel),
                                  hipFuncAttributeMaxDynamicSharedMemorySize, 131072);
        attr_done = true;
    }

    if (ws_size >= need_full) {
        // one fused prep launch: blocks [0,8192) build w, [8192,24576) convert x
        prep_kernel<<<24576, 256, 0, stream>>>(x, wh, wmed, wl, hm, mm, scale, wbf, xbf);
        gemm256_kernel<<<dim3(512), dim3(512), 131072, stream>>>(xbf, wbf, bias, out);
    } else {
        prep_kernel<<<8192, 256, 0, stream>>>(x, wh, wmed, wl, hm, mm, scale, wbf, wbf);
        dim3 grid(N_DIM / 128, M_DIM / 128);
        gemm_fused_kernel<<<grid, 256, 0, stream>>>(x, wbf, bias, out);
    }
}